// Round 2
// baseline (165.672 us; speedup 1.0000x reference)
//
#include <hip/hip_runtime.h>

#define R 256
#define T 32
#define BATCH 32
#define YS 64

#define TILE 32
#define HW 34          // hidden tile extent = TILE + 2
#define XW 36          // x-tile extent     = TILE + 4
#define HSTRIDE 36     // padded hidden row stride (keeps float4 alignment)
#define CG 8           // channels per group (4 groups of 8)

// ---------------------------------------------------------------------------
// Kernel A: x[b,p,q] = sum_t Ht[t,p,q] * yt[b,t,p>>2,q>>2]
// ---------------------------------------------------------------------------
__global__ __launch_bounds__(256) void einsum_kernel(
    const float* __restrict__ yt, const float* __restrict__ Ht,
    float* __restrict__ x) {
  const int r  = blockIdx.x & 3;          // sub-row 0..3
  const int yy = (blockIdx.x >> 2) & 63;  // yt row 0..63
  const int bg = blockIdx.x >> 8;         // batch group 0..7 (4 batches each)
  const int p  = yy * 4 + r;
  const int q  = threadIdx.x;

  float ht[T];
#pragma unroll
  for (int t = 0; t < T; ++t) ht[t] = Ht[(t * R + p) * R + q];

  __shared__ float yts[T * YS];
  const int q4 = q >> 2;

  for (int bi = 0; bi < 4; ++bi) {
    const int b = bg * 4 + bi;
    // stage yt[b, :, yy, :] (2048 floats) into LDS, coalesced
#pragma unroll
    for (int i = 0; i < 8; ++i) {
      int j  = threadIdx.x + i * 256;      // 0..2047
      int t  = j >> 6;
      int xx = j & 63;
      yts[j] = yt[((b * T + t) * YS + yy) * YS + xx];
    }
    __syncthreads();
    float acc = 0.f;
#pragma unroll
    for (int t = 0; t < T; ++t) acc += ht[t] * yts[t * YS + q4];
    x[(b * R + p) * R + q] = acc;
    __syncthreads();
  }
}

// ---------------------------------------------------------------------------
// Kernel B: fused Conv(1->32,3x3,SAME) -> ReLU -> Conv(32->1,3x3,SAME)
// Hidden activations outside the global image must be ZERO for conv2's SAME
// padding (they don't exist) — mask the halo store.
// ---------------------------------------------------------------------------
__global__ __launch_bounds__(256) void conv_fused_kernel(
    const float* __restrict__ x, const float* __restrict__ W1,
    const float* __restrict__ b1, const float* __restrict__ W2,
    const float* __restrict__ b2, float* __restrict__ out) {
  __shared__ float xs[XW * XW];            // 5184 B
  __shared__ float hs[CG * HW * HSTRIDE];  // 8*34*36*4 = 39168 B

  const int tid  = threadIdx.x;
  const int b    = blockIdx.x >> 6;
  const int tile = blockIdx.x & 63;
  const int oy0  = (tile >> 3) * TILE;
  const int ox0  = (tile & 7) * TILE;
  const float* xb = x + b * R * R;

  // --- stage x tile with halo 2, zero-padded (SAME) ---
  for (int i = tid; i < XW * XW; i += 256) {
    int rr = i / XW, cc = i % XW;
    int gy = oy0 - 2 + rr, gx = ox0 - 2 + cc;
    float v = 0.f;
    if (gy >= 0 && gy < R && gx >= 0 && gx < R) v = xb[gy * R + gx];
    xs[i] = v;
  }
  __syncthreads();

  // --- preload each thread's 3x3 patches for its hidden pixels (regs) ---
  float patch[5][9];
  int   hy_r[5], hx_r[5];
  bool  valid[5];   // valid hidden-tile slot AND inside global image
#pragma unroll
  for (int it = 0; it < 5; ++it) {
    int px = tid + it * 256;
    bool slot = (px < HW * HW);
    int hy = slot ? (px / HW) : 0;
    int hx = slot ? (px % HW) : 0;
    hy_r[it] = hy;
    hx_r[it] = hx;
    // global hidden coords; outside image => hidden value is zero (conv2 SAME)
    int ghy = oy0 - 1 + hy, ghx = ox0 - 1 + hx;
    bool inimg = (ghy >= 0) & (ghy < R) & (ghx >= 0) & (ghx < R);
    valid[it] = slot;
#pragma unroll
    for (int k = 0; k < 9; ++k) patch[it][k] = 0.f;
    if (slot && inimg) {
#pragma unroll
      for (int ky = 0; ky < 3; ++ky)
#pragma unroll
        for (int kx = 0; kx < 3; ++kx)
          patch[it][ky * 3 + kx] = xs[(hy + ky) * XW + hx + kx];
    }
    // record whether to write a computed value or forced zero
    if (slot && !inimg) {
      // mark by clearing patch (all-zero) AND flag via hy/hx retained;
      // we force-store zero below using valid_img mask
    }
    // pack inimg into valid: we need both; reuse arrays
    hy_r[it] = hy | (inimg ? 0 : 0x10000);  // bit16 = out-of-image flag
  }

  const int oy_l = tid >> 3;         // 0..31
  const int ox_l = (tid & 7) * 4;    // 0,4,...,28
  const float bias2 = b2[0];
  float acc[4] = {bias2, bias2, bias2, bias2};

  for (int cg = 0; cg < 4; ++cg) {
    // ---- conv1 + relu for 8 channels into LDS ----
#pragma unroll
    for (int c = 0; c < CG; ++c) {
      const int ch = cg * CG + c;        // wave-uniform -> scalar loads
      const float bias = b1[ch];
#pragma unroll
      for (int it = 0; it < 5; ++it) {
        if (valid[it]) {
          const int hy = hy_r[it] & 0xffff;
          const bool oob = (hy_r[it] >> 16) != 0;
          float h = bias;
#pragma unroll
          for (int k = 0; k < 9; ++k) h += W1[ch * 9 + k] * patch[it][k];
          h = fmaxf(h, 0.f);
          if (oob) h = 0.f;            // hidden px outside image: conv2 pad
          hs[c * (HW * HSTRIDE) + hy * HSTRIDE + hx_r[it]] = h;
        }
      }
    }
    __syncthreads();

    // ---- conv2 partial sum over these 8 channels ----
#pragma unroll
    for (int c = 0; c < CG; ++c) {
      const int ch = cg * CG + c;
#pragma unroll
      for (int dy = 0; dy < 3; ++dy) {
        const float* row = &hs[c * (HW * HSTRIDE) + (oy_l + dy) * HSTRIDE + ox_l];
        float4 v4 = *(const float4*)row;        // ds_read_b128
        float2 v2 = *(const float2*)(row + 4);  // ds_read_b64
        float v[6] = {v4.x, v4.y, v4.z, v4.w, v2.x, v2.y};
#pragma unroll
        for (int dx = 0; dx < 3; ++dx) {
          const float w = W2[ch * 9 + dy * 3 + dx];  // scalar load
#pragma unroll
          for (int j = 0; j < 4; ++j) acc[j] += w * v[j + dx];
        }
      }
    }
    __syncthreads();
  }

  float4 o = {acc[0], acc[1], acc[2], acc[3]};
  *(float4*)&out[b * R * R + (oy0 + oy_l) * R + ox0 + ox_l] = o;
}

// ---------------------------------------------------------------------------
extern "C" void kernel_launch(void* const* d_in, const int* in_sizes, int n_in,
                              void* d_out, int out_size, void* d_ws, size_t ws_size,
                              hipStream_t stream) {
  const float* yt = (const float*)d_in[0];  // (32,32,64,64)
  const float* Ht = (const float*)d_in[1];  // (32,256,256)
  const float* W1 = (const float*)d_in[2];  // (32,1,3,3)
  const float* b1 = (const float*)d_in[3];  // (32,)
  const float* W2 = (const float*)d_in[4];  // (1,32,3,3)
  const float* b2 = (const float*)d_in[5];  // (1,)
  float* outp = (float*)d_out;              // (32,1,256,256)
  float* x    = (float*)d_ws;               // 32*256*256 floats = 8 MB scratch

  einsum_kernel<<<2048, 256, 0, stream>>>(yt, Ht, x);
  conv_fused_kernel<<<2048, 256, 0, stream>>>(x, W1, b1, W2, b2, outp);
}

// Round 3
// 155.679 us; speedup vs baseline: 1.0642x; 1.0642x over previous
//
#include <hip/hip_runtime.h>

#define R 256
#define T 32

#define TILE 32
#define XW 36           // x-tile extent (halo 2 each side)
#define HROWS 34        // hidden rows  (-1..32) -> hy 0..33
#define HSTR 36         // hidden row stride, word w = hidden col + 1 (cols -1..32 -> w 0..33)
#define CPLANE 1236     // channel plane stride in words (34*36=1224 + 12 pad; 1236%32=20 -> 8cl distinct bank groups; 1236%4==0 keeps 16B align)

// ---------------------------------------------------------------------------
// Kernel A: x[b,p,q] = sum_t Ht[t,p,q] * yt[b,t,p>>2,q>>2]
// Grid 1024: idx = r*256 + (yy*4 + bq).  Block: 1 p-row, 8 batches, 256 q.
// yt[8b,32t,yy,64xx] staged once (64 KB, one barrier); Ht held as float2[32].
// ---------------------------------------------------------------------------
__global__ __launch_bounds__(256) void einsum_kernel(
    const float* __restrict__ yt, const float* __restrict__ Ht,
    float* __restrict__ x) {
  const int idx = blockIdx.x;
  const int r   = idx >> 8;          // 0..3
  const int yy  = (idx & 255) >> 2;  // 0..63
  const int bq  = idx & 3;           // 0..3
  const int p   = yy * 4 + r;
  const int b0  = bq * 8;
  const int tid = threadIdx.x;
  const int qp  = tid & 127;         // q-pair index: q = 2qp, 2qp+1
  const int bh  = tid >> 7;          // batch half 0/1
  const int q4  = qp >> 1;           // 0..63

  __shared__ float yts[8 * 32 * 64];  // [b_l][t][xx] — 64 KB, layout-preserving

#pragma unroll
  for (int i = 0; i < 16; ++i) {
    int f4  = tid + i * 256;          // 0..4095 float4s
    int b_l = f4 >> 9;
    int t   = (f4 >> 4) & 31;
    int xx4 = f4 & 15;
    float4 v = *(const float4*)(yt + (((size_t)(b0 + b_l) * T + t) * 64 + yy) * 64 + xx4 * 4);
    *(float4*)(yts + f4 * 4) = v;
  }

  // Ht[t, p, 2qp..2qp+1] in regs (coalesced float2, lanes consecutive qp)
  float2 ht[T];
  const float* Hp = Ht + p * R + 2 * qp;
#pragma unroll
  for (int t = 0; t < T; ++t) ht[t] = *(const float2*)(Hp + (size_t)t * R * R);

  __syncthreads();

#pragma unroll
  for (int bi = 0; bi < 4; ++bi) {
    const int b_l = bh * 4 + bi;
    const float* ys = yts + b_l * 2048 + q4;  // reads: bank=q4%32, 2-lane broadcast, conflict-free
    float ax = 0.f, ay = 0.f;
#pragma unroll
    for (int t = 0; t < T; ++t) {
      float yv = ys[t * 64];
      ax += ht[t].x * yv;
      ay += ht[t].y * yv;
    }
    float2 o = {ax, ay};
    *(float2*)(x + ((size_t)(b0 + b_l) * R + p) * R + 2 * qp) = o;
  }
}

// ---------------------------------------------------------------------------
// Kernel B: fused Conv(1->32,3x3) -> ReLU -> Conv(32->1,3x3), SAME padding.
// conv2 lane map: g=lane>>3 (col granule), cl=lane&7 (channel) -> stride-1
// b128 reads, conflict-free; rolling-row (each hs row read once); partials
// reduced with shfl_xor(1,2,4).
// ---------------------------------------------------------------------------
__global__ __launch_bounds__(256) void conv_fused_kernel(
    const float* __restrict__ x, const float* __restrict__ W1,
    const float* __restrict__ b1, const float* __restrict__ W2,
    const float* __restrict__ b2, float* __restrict__ out) {
  __shared__ float xs[XW * XW];      // 5184 B
  __shared__ float hs[8 * CPLANE];   // 39552 B

  const int tid  = threadIdx.x;
  const int b    = blockIdx.x >> 6;
  const int tile = blockIdx.x & 63;
  const int oy0  = (tile >> 3) * TILE;
  const int ox0  = (tile & 7) * TILE;
  const float* xb = x + (size_t)b * R * R;

  // --- stage x tile with halo 2, zero-padded ---
  for (int i = tid; i < XW * XW; i += 256) {
    int rr = i / XW, cc = i % XW;
    int gy = oy0 - 2 + rr, gx = ox0 - 2 + cc;
    float v = 0.f;
    if (gy >= 0 && gy < R && gx >= 0 && gx < R) v = xb[gy * R + gx];
    xs[i] = v;
  }
  __syncthreads();

  // --- preload 3x3 patches for this thread's hidden px slots (34x34 grid) ---
  float patch[5][9];
  int  hy_r[5], hx_r[5];
  bool slot[5], oob[5];
#pragma unroll
  for (int it = 0; it < 5; ++it) {
    int px = tid + it * 256;
    slot[it] = (px < HROWS * HROWS);   // 1156
    int hy = slot[it] ? (px / 34) : 0; // hy = hidden row + 1 (0..33)
    int hx = slot[it] ? (px % 34) : 0; // hx = hidden col + 1 (0..33)
    hy_r[it] = hy;
    hx_r[it] = hx;
    int ghy = oy0 - 1 + hy, ghx = ox0 - 1 + hx;  // global hidden coords
    oob[it] = !((ghy >= 0) & (ghy < R) & (ghx >= 0) & (ghx < R));
#pragma unroll
    for (int ky = 0; ky < 3; ++ky)
#pragma unroll
      for (int kx = 0; kx < 3; ++kx)
        patch[it][ky * 3 + kx] = slot[it] ? xs[(hy + ky) * XW + hx + kx] : 0.f;
  }

  const int wv   = tid >> 6;   // wave 0..3: output rows 8wv..8wv+7
  const int lane = tid & 63;
  const int g    = lane >> 3;  // output col granule: px 4g..4g+3
  const int cl   = lane & 7;   // channel within group

  float acc[8][4];
#pragma unroll
  for (int ai = 0; ai < 8; ++ai)
#pragma unroll
    for (int j = 0; j < 4; ++j) acc[ai][j] = 0.f;

  const float* hb = hs + cl * CPLANE + (8 * wv) * HSTR + 4 * g;

  for (int cg = 0; cg < 4; ++cg) {
    // ---- conv1 + relu for channels cg*8..cg*8+7 into hs planes 0..7 ----
#pragma unroll
    for (int c = 0; c < 8; ++c) {
      const int ch = cg * 8 + c;          // wave-uniform -> scalar weight loads
      const float bias = b1[ch];
#pragma unroll
      for (int it = 0; it < 5; ++it) {
        if (slot[it]) {
          float h = bias;
#pragma unroll
          for (int k = 0; k < 9; ++k) h += W1[ch * 9 + k] * patch[it][k];
          h = fmaxf(h, 0.f);
          if (oob[it]) h = 0.f;           // conv2 SAME: outside-image hidden = 0
          hs[c * CPLANE + hy_r[it] * HSTR + hx_r[it]] = h;
        }
      }
    }
    __syncthreads();

    // ---- conv2 partials: rolling rows, each hs row read once ----
    float w2[9];
#pragma unroll
    for (int k = 0; k < 9; ++k) w2[k] = W2[(cg * 8 + cl) * 9 + k];

#pragma unroll
    for (int hy = 0; hy < 10; ++hy) {     // global hy = 8wv+hy in [0,33]
      float4 v4 = *(const float4*)(hb + hy * HSTR);
      float2 v2 = *(const float2*)(hb + hy * HSTR + 4);
      float v[6] = {v4.x, v4.y, v4.z, v4.w, v2.x, v2.y};
#pragma unroll
      for (int dy = 0; dy < 3; ++dy) {
        int ai = hy - dy;
        if (ai >= 0 && ai < 8) {
#pragma unroll
          for (int dx = 0; dx < 3; ++dx) {
            float wgt = w2[dy * 3 + dx];
#pragma unroll
            for (int j = 0; j < 4; ++j) acc[ai][j] += wgt * v[j + dx];
          }
        }
      }
    }
    __syncthreads();
  }

  // ---- reduce over channels (lanes xor 1,2,4) and store ----
  const float bias2 = b2[0];
#pragma unroll
  for (int ai = 0; ai < 8; ++ai)
#pragma unroll
    for (int j = 0; j < 4; ++j) {
      float v = acc[ai][j];
      v += __shfl_xor(v, 1);
      v += __shfl_xor(v, 2);
      v += __shfl_xor(v, 4);
      acc[ai][j] = v;
    }
  if (cl == 0) {
#pragma unroll
    for (int ai = 0; ai < 8; ++ai) {
      float4 o = {acc[ai][0] + bias2, acc[ai][1] + bias2,
                  acc[ai][2] + bias2, acc[ai][3] + bias2};
      *(float4*)(out + (size_t)b * R * R + (oy0 + 8 * wv + ai) * R + ox0 + 4 * g) = o;
    }
  }
}

// ---------------------------------------------------------------------------
extern "C" void kernel_launch(void* const* d_in, const int* in_sizes, int n_in,
                              void* d_out, int out_size, void* d_ws, size_t ws_size,
                              hipStream_t stream) {
  const float* yt = (const float*)d_in[0];  // (32,32,64,64)
  const float* Ht = (const float*)d_in[1];  // (32,256,256)
  const float* W1 = (const float*)d_in[2];  // (32,1,3,3)
  const float* b1 = (const float*)d_in[3];  // (32,)
  const float* W2 = (const float*)d_in[4];  // (1,32,3,3)
  const float* b2 = (const float*)d_in[5];  // (1,)
  float* outp = (float*)d_out;              // (32,1,256,256)
  float* x    = (float*)d_ws;               // 8 MB scratch

  einsum_kernel<<<1024, 256, 0, stream>>>(yt, Ht, x);
  conv_fused_kernel<<<2048, 256, 0, stream>>>(x, W1, b1, W2, b2, outp);
}